// Round 1
// 837.865 us; speedup vs baseline: 1.0484x; 1.0484x over previous
//
#include <hip/hip_runtime.h>
#include <hip/hip_fp16.h>

// Problem constants (from reference)
#define NN   1000000
#define D    128
#define DV4  32          // D / 4 floats per float4
#define DH   128         // halves per row
#define BATCH 1024
#define LW   40          // walk length
#define WIN  5
#define NP   370         // pairs per walk
#define NEG  5
#define NPB  (NP * NEG)  // 1850 negatives per walk
#define NPAIR_TOT (BATCH * NP)   // 378880

// Pair index table, generated to match reference _make_pair_idx loop order exactly.
struct Tab { short src[NP]; short dst[NP]; };
constexpr Tab mk_tab() {
  Tab t{};
  int n = 0;
  for (int i = 0; i < LW; i++) {
    int lo = i - WIN; if (lo < 0) lo = 0;
    for (int j = lo; j < i; j++) { t.src[n] = (short)j; t.dst[n] = (short)i; n++; }
    int hi = i + 1 + WIN; if (hi > LW) hi = LW;
    for (int j = i + 1; j < hi; j++) { t.src[n] = (short)j; t.dst[n] = (short)i; n++; }
  }
  return t;
}
__constant__ Tab g_tab = mk_tab();

__device__ __forceinline__ unsigned h2u(__half2 h) {
  union { __half2 h; unsigned u; } cv; cv.h = h; return cv.u;
}

// Kernel 1: gather ctx rows for all B*L flat positions into contiguous fp16 ws.
// 16 lanes per row, each converts 8 floats -> 8 halves (16 B write).
__global__ __launch_bounds__(256) void gather_ctx_h(
    const float4* __restrict__ ctx, const int* __restrict__ walk,
    uint4* __restrict__ out) {
  int g = blockIdx.x * blockDim.x + threadIdx.x;   // [0, B*L*16)
  int p = g >> 4;      // flat position
  int c = g & 15;      // 16-byte column
  int idx = walk[p];   // broadcast within 16 threads
  float4 v0 = ctx[(long long)idx * DV4 + 2 * c];
  float4 v1 = ctx[(long long)idx * DV4 + 2 * c + 1];
  uint4 o;
  o.x = h2u(__float22half2_rn(make_float2(v0.x, v0.y)));
  o.y = h2u(__float22half2_rn(make_float2(v0.z, v0.w)));
  o.z = h2u(__float22half2_rn(make_float2(v1.x, v1.y)));
  o.w = h2u(__float22half2_rn(make_float2(v1.z, v1.w)));
  out[p * 16 + c] = o;
}

__device__ __forceinline__ float dot4(float4 a, float4 c) {
  return a.x * c.x + a.y * c.y + a.z * c.z + a.w * c.w;
}
// fp16 row chunk (4 halves in uint2) dotted against 4 fp32 node elements.
__device__ __forceinline__ float dot_h(float4 a, uint2 r) {
  __half2 h0 = *reinterpret_cast<const __half2*>(&r.x);
  __half2 h1 = *reinterpret_cast<const __half2*>(&r.y);
  float2 f0 = __half22float2(h0);
  float2 f1 = __half22float2(h1);
  return a.x * f0.x + a.y * f0.y + a.z * f1.x + a.w * f1.y;
}
__device__ __forceinline__ float red32(float p) {
  p += __shfl_xor(p, 1);  p += __shfl_xor(p, 2);  p += __shfl_xor(p, 4);
  p += __shfl_xor(p, 8);  p += __shfl_xor(p, 16);
  return p;
}
// Reduce 4 independent per-lane partials across a 32-lane group in 9 shuffles.
// Result: lane with (l&3)==k holds the full 32-lane sum of pk.
__device__ __forceinline__ float red4x32(float p0, float p1, float p2, float p3, int l) {
  float q0 = p0 + __shfl_xor(p0, 1);
  float q1 = p1 + __shfl_xor(p1, 1);
  float q2 = p2 + __shfl_xor(p2, 1);
  float q3 = p3 + __shfl_xor(p3, 1);
  float m01 = (l & 1) ? q1 : q0;
  float m23 = (l & 1) ? q3 : q2;
  m01 += __shfl_xor(m01, 2);
  m23 += __shfl_xor(m23, 2);
  float m = (l & 2) ? m23 : m01;
  m += __shfl_xor(m, 4);
  m += __shfl_xor(m, 8);
  m += __shfl_xor(m, 16);
  return m;
}

// Kernel 2: one block per walk, 512 threads = 16 groups of 32 lanes.
// LDS: node rows fp32 (20 KiB) + neg indices (7.4 KB). ~28 KiB -> 4 blocks/CU,
// full 32-wave occupancy at grid=1024.
__global__ __launch_bounds__(512) void sgns_kernel(
    const float4* __restrict__ node_embed,
    const float4* __restrict__ ctx_embed,   // fallback path only
    const int* __restrict__ walk,
    const int* __restrict__ neg_idx,
    const __half* __restrict__ ctxh,        // gathered fp16 ctx in ws (may be null)
    float* __restrict__ out) {
  __shared__ float4 sNode[LW * DV4];   // 20480 B
  __shared__ int sIdx[NPB];            // 7400 B

  const int b = blockIdx.x;
  const int tid = threadIdx.x;

  // Stage node rows: 1280 float4, 512 threads -> 2.5 iterations.
  for (int e = tid; e < LW * DV4; e += 512) {
    int row = e >> 5;
    int c = e & 31;
    int idx = walk[b * LW + row];
    sNode[e] = node_embed[(long long)idx * DV4 + c];
  }
  // Stage negative indices (coalesced int reads).
  for (int t = tid; t < NPB; t += 512) sIdx[t] = neg_idx[b * NPB + t];
  __syncthreads();

  const int grp = tid >> 5;   // 16 groups
  const int l = tid & 31;
  float acc = 0.f;

  // Per-walk gathered ctx slice (fp16, L1/L2-hot, 10 KB).
  const __half* cwalk = ctxh ? (ctxh + (size_t)b * LW * DH) : nullptr;

  // Positive pairs, unrolled x4 with the 9-shuffle combined reduction.
  int k = grp;
  for (; k + 48 < NP; k += 64) {
    int s0 = g_tab.src[k],      d0 = g_tab.dst[k];
    int s1 = g_tab.src[k + 16], d1 = g_tab.dst[k + 16];
    int s2 = g_tab.src[k + 32], d2 = g_tab.dst[k + 32];
    int s3 = g_tab.src[k + 48], d3 = g_tab.dst[k + 48];
    float4 a0 = sNode[s0 * DV4 + l];
    float4 a1 = sNode[s1 * DV4 + l];
    float4 a2 = sNode[s2 * DV4 + l];
    float4 a3 = sNode[s3 * DV4 + l];
    float p0, p1, p2, p3;
    if (cwalk) {
      uint2 r0 = *(const uint2*)(cwalk + d0 * DH + l * 4);
      uint2 r1 = *(const uint2*)(cwalk + d1 * DH + l * 4);
      uint2 r2 = *(const uint2*)(cwalk + d2 * DH + l * 4);
      uint2 r3 = *(const uint2*)(cwalk + d3 * DH + l * 4);
      p0 = dot_h(a0, r0); p1 = dot_h(a1, r1);
      p2 = dot_h(a2, r2); p3 = dot_h(a3, r3);
    } else {
      p0 = dot4(a0, (ctx_embed + (long long)walk[b * LW + d0] * DV4)[l]);
      p1 = dot4(a1, (ctx_embed + (long long)walk[b * LW + d1] * DV4)[l]);
      p2 = dot4(a2, (ctx_embed + (long long)walk[b * LW + d2] * DV4)[l]);
      p3 = dot4(a3, (ctx_embed + (long long)walk[b * LW + d3] * DV4)[l]);
    }
    float m = red4x32(p0, p1, p2, p3, l);
    if (l < 4) {
      float sc = fminf(fmaxf(m, -6.f), 6.f);
      acc += __logf(1.f + __expf(-sc));   // -log_sigmoid(sc)
    }
  }
  for (; k < NP; k += 16) {
    int s = g_tab.src[k];
    int d = g_tab.dst[k];
    float4 a = sNode[s * DV4 + l];
    float p;
    if (cwalk) {
      uint2 r = *(const uint2*)(cwalk + d * DH + l * 4);
      p = dot_h(a, r);
    } else {
      p = dot4(a, (ctx_embed + (long long)walk[b * LW + d] * DV4)[l]);
    }
    p = red32(p);
    if (l == 0) {
      float sc = fminf(fmaxf(p, -6.f), 6.f);
      acc += __logf(1.f + __expf(-sc));
    }
  }

  // Negative pairs, unrolled x4: 4 independent fp16 row loads in flight.
  int t = grp;
  for (; t + 48 < NPB; t += 64) {
    int j0 = sIdx[t], j1 = sIdx[t + 16], j2 = sIdx[t + 32], j3 = sIdx[t + 48];
    float4 a0 = sNode[g_tab.dst[t / NEG] * DV4 + l];
    float4 a1 = sNode[g_tab.dst[(t + 16) / NEG] * DV4 + l];
    float4 a2 = sNode[g_tab.dst[(t + 32) / NEG] * DV4 + l];
    float4 a3 = sNode[g_tab.dst[(t + 48) / NEG] * DV4 + l];
    float p0, p1, p2, p3;
    if (ctxh) {
      uint2 r0 = *(const uint2*)(ctxh + (size_t)j0 * DH + l * 4);
      uint2 r1 = *(const uint2*)(ctxh + (size_t)j1 * DH + l * 4);
      uint2 r2 = *(const uint2*)(ctxh + (size_t)j2 * DH + l * 4);
      uint2 r3 = *(const uint2*)(ctxh + (size_t)j3 * DH + l * 4);
      p0 = dot_h(a0, r0); p1 = dot_h(a1, r1);
      p2 = dot_h(a2, r2); p3 = dot_h(a3, r3);
    } else {
      p0 = dot4(a0, (ctx_embed + (long long)walk[j0] * DV4)[l]);
      p1 = dot4(a1, (ctx_embed + (long long)walk[j1] * DV4)[l]);
      p2 = dot4(a2, (ctx_embed + (long long)walk[j2] * DV4)[l]);
      p3 = dot4(a3, (ctx_embed + (long long)walk[j3] * DV4)[l]);
    }
    float m = red4x32(p0, p1, p2, p3, l);
    if (l < 4) {
      float sc = fminf(fmaxf(m, -6.f), 6.f);
      acc += __logf(1.f + __expf(sc));    // -log_sigmoid(-sc)
    }
  }
  for (; t < NPB; t += 16) {
    int j = sIdx[t];
    float4 a = sNode[g_tab.dst[t / NEG] * DV4 + l];
    float p;
    if (ctxh) {
      uint2 r = *(const uint2*)(ctxh + (size_t)j * DH + l * 4);
      p = dot_h(a, r);
    } else {
      p = dot4(a, (ctx_embed + (long long)walk[j] * DV4)[l]);
    }
    p = red32(p);
    if (l == 0) {
      float sc = fminf(fmaxf(p, -6.f), 6.f);
      acc += __logf(1.f + __expf(sc));
    }
  }

  // Block reduction.
  acc += __shfl_xor(acc, 1);  acc += __shfl_xor(acc, 2);  acc += __shfl_xor(acc, 4);
  acc += __shfl_xor(acc, 8);  acc += __shfl_xor(acc, 16); acc += __shfl_xor(acc, 32);
  __syncthreads();                       // done reading sNode; reuse as scratch
  float* sRed = (float*)sNode;
  if ((tid & 63) == 0) sRed[tid >> 6] = acc;
  __syncthreads();
  if (tid == 0) {
    float s = 0.f;
    for (int w = 0; w < 8; w++) s += sRed[w];
    atomicAdd(out, s * (1.f / (float)NPAIR_TOT));
  }
}

extern "C" void kernel_launch(void* const* d_in, const int* in_sizes, int n_in,
                              void* d_out, int out_size, void* d_ws, size_t ws_size,
                              hipStream_t stream) {
  const float* node_embed = (const float*)d_in[0];
  const float* ctx_embed  = (const float*)d_in[1];
  const int*   walk       = (const int*)d_in[2];
  const int*   neg        = (const int*)d_in[3];
  float* out = (float*)d_out;

  hipMemsetAsync(d_out, 0, sizeof(float), stream);

  const size_t need = (size_t)BATCH * LW * DH * sizeof(__half);  // ~10.5 MB
  __half* ctxh = nullptr;
  if (ws_size >= need) {
    ctxh = (__half*)d_ws;
    int total = BATCH * LW * 16;       // 655,360 threads
    gather_ctx_h<<<total / 256, 256, 0, stream>>>(
        (const float4*)ctx_embed, walk, (uint4*)ctxh);
  }

  sgns_kernel<<<BATCH, 512, 0, stream>>>(
      (const float4*)node_embed, (const float4*)ctx_embed, walk, neg, ctxh, out);
}